// Round 5
// baseline (238.055 us; speedup 1.0000x reference)
//
#include <hip/hip_runtime.h>
#include <math.h>
#include <stdint.h>

// TreeLSTM, 32 complete binary trees depth 10, heap order, d=128.
// R5 = R4 with the LDS-pointer-array compile fix:
//   tail (dep6..0): h double-buffered in LDS (parity ternary, not pointer
//   array), c carried in lane registers (producer/consumer lane layouts
//   match), wx prefetched ahead of the MFMAs, dep/group loops fully unrolled.

#define NTREES 32
#define MTREE 2047
#define NNODES (NTREES * MTREE)   // 65504

typedef __attribute__((ext_vector_type(8))) short bf16x8;
typedef __attribute__((ext_vector_type(4))) float f32x4;

__device__ __forceinline__ float sigmoidf_(float x) {
    return 1.0f / (1.0f + __expf(-x));
}
__device__ __forceinline__ float tanhf_(float x) {
    x = fminf(fmaxf(x, -10.0f), 10.0f);
    float e = __expf(2.0f * x);
    return (e - 1.0f) / (e + 1.0f);
}
__device__ __forceinline__ float bf2f(uint16_t b) {
    union { uint32_t u; float f; } v; v.u = ((uint32_t)b) << 16; return v.f;
}
__device__ __forceinline__ uint16_t f2bf(float f) {
    union { float f; uint32_t u; } v; v.f = f;
    uint32_t r = v.u + 0x7FFF + ((v.u >> 16) & 1);   // RNE
    return (uint16_t)(r >> 16);
}
__device__ __forceinline__ uint4 pack_bf8(float4 a, float4 b) {
    uint4 r;
    r.x = (uint32_t)f2bf(a.x) | ((uint32_t)f2bf(a.y) << 16);
    r.y = (uint32_t)f2bf(a.z) | ((uint32_t)f2bf(a.w) << 16);
    r.z = (uint32_t)f2bf(b.x) | ((uint32_t)f2bf(b.y) << 16);
    r.w = (uint32_t)f2bf(b.z) | ((uint32_t)f2bf(b.w) << 16);
    return r;
}
__device__ __forceinline__ bf16x8 bfadd8(bf16x8 a, bf16x8 b) {
    bf16x8 r;
#pragma unroll
    for (int e = 0; e < 8; ++e)
        r[e] = (short)f2bf(bf2f((uint16_t)a[e]) + bf2f((uint16_t)b[e]));
    return r;
}

// Swizzled LDS layout: bf16 rows of 128 (16 chunks of 16B), XOR by row&7.
#define SWZ(row, chunk) ((row) * 128 + (((chunk) ^ ((row) & 7)) * 8))

// ---------------------------------------------------------------------------
__global__ __launch_bounds__(128) void prep_k(const float* __restrict__ Wiou,
                                              const float* __restrict__ Wf,
                                              const float* __restrict__ Uiou,
                                              const float* __restrict__ Uf,
                                              const float* __restrict__ biou,
                                              const float* __restrict__ bf,
                                              uint16_t* __restrict__ WT,
                                              uint16_t* __restrict__ UT,
                                              float* __restrict__ biasS) {
    int n = blockIdx.x, k = threadIdx.x;
    if (n < 512) {
        WT[n * 128 + k] = f2bf(n < 384 ? Wiou[k * 384 + n] : Wf[k * 128 + (n - 384)]);
    } else if (n < 1024) {
        int m = n - 512;
        UT[m * 128 + k] = f2bf(m < 384 ? Uiou[k * 384 + m] : Uf[k * 128 + (m - 384)]);
    } else {
#pragma unroll
        for (int r = 0; r < 4; ++r) {
            int j = r * 128 + k;
            biasS[j] = j < 384 ? biou[j] : bf[j - 384];
        }
    }
}

// ---------------------------------------------------------------------------
// Fused GEMM + leaf epilogue (unchanged from R3).
__global__ __launch_bounds__(512, 2) void gemm_leaf_k(const float* __restrict__ F,
                                                      const uint16_t* __restrict__ WT,
                                                      const float* __restrict__ biasS,
                                                      uint16_t* __restrict__ wx,
                                                      float* __restrict__ h,
                                                      float* __restrict__ c) {
    __shared__ uint16_t Fs[64 * 128];
    const int tid = threadIdx.x;
    const int w = tid >> 6, lane = tid & 63, q = lane >> 4, l15 = lane & 15;
    const int n0 = blockIdx.x * 64;

#pragma unroll
    for (int r = 0; r < 2; ++r) {
        int ci = r * 512 + tid;
        int row = ci >> 4, cx = ci & 15;
        int v = n0 + row; v = v < NNODES ? v : NNODES - 1;
        const float* src = F + (size_t)v * 128 + cx * 8;
        float4 f0 = *(const float4*)src;
        float4 f1 = *(const float4*)(src + 4);
        *(uint4*)&Fs[SWZ(row, cx)] = pack_bf8(f0, f1);
    }
    bf16x8 aW[4][4];
    float4 bias4[4];
#pragma unroll
    for (int s = 0; s < 4; ++s) {
        int row = (w + s * 8) * 16 + l15;
#pragma unroll
        for (int kc = 0; kc < 4; ++kc)
            aW[s][kc] = *(const bf16x8*)(WT + (size_t)row * 128 + kc * 32 + q * 8);
        bias4[s] = *(const float4*)(biasS + (w + s * 8) * 16 + q * 4);
    }
    __syncthreads();

#pragma unroll
    for (int nt = 0; nt < 4; ++nt) {
        bf16x8 b[4];
#pragma unroll
        for (int kc = 0; kc < 4; ++kc)
            b[kc] = *(const bf16x8*)&Fs[SWZ(nt * 16 + l15, kc * 4 + q)];
        f32x4 acc[4] = {};
#pragma unroll
        for (int s = 0; s < 4; ++s)
#pragma unroll
            for (int kc = 0; kc < 4; ++kc)
                acc[s] = __builtin_amdgcn_mfma_f32_16x16x32_bf16(aW[s][kc], b[kc], acc[s], 0, 0, 0);

        int node = n0 + nt * 16 + l15;
        bool nvalid = node < NNODES;
        int v = nvalid ? node : NNODES - 1;
        int tree = v / 2047;
        int j = v - tree * 2047;
        bool leaf = j >= 1023;
        float pi[4], po[4], pu[4], pf[4];
#pragma unroll
        for (int r = 0; r < 4; ++r) {
            pi[r] = acc[0][r] + bias4[0][r];
            po[r] = acc[1][r] + bias4[1][r];
            pu[r] = acc[2][r] + bias4[2][r];
            pf[r] = acc[3][r] + bias4[3][r];
        }
        int colb = w * 16 + q * 4;
        if (nvalid && leaf) {
            float cv[4], hv[4];
#pragma unroll
            for (int r = 0; r < 4; ++r) {
                float iv = sigmoidf_(pi[r]);
                float ov = sigmoidf_(po[r]);
                float uv = tanhf_(pu[r]);
                float cn = iv * uv;
                cv[r] = cn;
                hv[r] = ov * tanhf_(cn);
            }
            *(float4*)&c[(size_t)v * 128 + colb] = *(float4*)cv;
            *(float4*)&h[(size_t)v * 128 + colb] = *(float4*)hv;
        }
        if (nvalid && !leaf) {
            ushort4 s0 = make_ushort4(f2bf(pi[0]), f2bf(pi[1]), f2bf(pi[2]), f2bf(pi[3]));
            ushort4 s1 = make_ushort4(f2bf(po[0]), f2bf(po[1]), f2bf(po[2]), f2bf(po[3]));
            ushort4 s2 = make_ushort4(f2bf(pu[0]), f2bf(pu[1]), f2bf(pu[2]), f2bf(pu[3]));
            ushort4 s3 = make_ushort4(f2bf(pf[0]), f2bf(pf[1]), f2bf(pf[2]), f2bf(pf[3]));
            uint16_t* wr = wx + (size_t)v * 512 + colb;
            *(ushort4*)(wr)       = s0;
            *(ushort4*)(wr + 128) = s1;
            *(ushort4*)(wr + 256) = s2;
            *(ushort4*)(wr + 384) = s3;
        }
    }
}

// ---------------------------------------------------------------------------
__device__ __forceinline__ void load_bU(const uint16_t* __restrict__ UT, bf16x8 bU[4][4]) {
    const int tid = threadIdx.x;
    const int w = tid >> 6, lane = tid & 63, q = lane >> 4, l15 = lane & 15;
#pragma unroll
    for (int s = 0; s < 4; ++s) {
        int row = (w + s * 8) * 16 + l15;
#pragma unroll
        for (int kc = 0; kc < 4; ++kc)
            bU[s][kc] = *(const bf16x8*)(UT + (size_t)row * 128 + kc * 32 + q * 8);
    }
}

// Climb group for the grid-parallel big levels (global h/c, unchanged from R3).
__device__ __forceinline__ void climb_group(const uint16_t* __restrict__ wx,
                                            float* __restrict__ h,
                                            float* __restrict__ c,
                                            uint16_t* Hc, uint16_t* HS, float* PS,
                                            const bf16x8 bU[4][4],
                                            int vp, int vc, int P) {
    const int tid = threadIdx.x;
    const int w = tid >> 6, lane = tid & 63, q = lane >> 4, l15 = lane & 15;

#pragma unroll
    for (int t = 0; t < 3; ++t) {
        int ci = t * 512 + tid;
        if (ci < 1024) {
            int row = ci >> 4, cx = ci & 15;
            uint4 val = make_uint4(0, 0, 0, 0);
            if (row < 2 * P) {
                const float* src = h + (size_t)(vc + row) * 128 + cx * 8;
                float4 f0 = *(const float4*)src;
                float4 f1 = *(const float4*)(src + 4);
                val = pack_bf8(f0, f1);
            }
            *(uint4*)&Hc[SWZ(row, cx)] = val;
        } else {
            int ci2 = ci - 1024;
            int prow = ci2 >> 4, cx = ci2 & 15;
            uint4 val = make_uint4(0, 0, 0, 0);
            if (prow < P) {
                const float* s0 = h + (size_t)(vc + 2 * prow) * 128 + cx * 8;
                const float* s1 = h + (size_t)(vc + 2 * prow + 1) * 128 + cx * 8;
                float4 a0 = *(const float4*)s0, a1 = *(const float4*)(s0 + 4);
                float4 b0 = *(const float4*)s1, b1 = *(const float4*)(s1 + 4);
                float4 u = {a0.x + b0.x, a0.y + b0.y, a0.z + b0.z, a0.w + b0.w};
                float4 v2 = {a1.x + b1.x, a1.y + b1.y, a1.z + b1.z, a1.w + b1.w};
                val = pack_bf8(u, v2);
            }
            *(uint4*)&HS[SWZ(prow, cx)] = val;
        }
    }
    __syncthreads();

    f32x4 accI[2][3] = {};
    f32x4 accF[4] = {};
#pragma unroll
    for (int mt = 0; mt < 2; ++mt) {
        bf16x8 a[4];
#pragma unroll
        for (int kc = 0; kc < 4; ++kc)
            a[kc] = *(const bf16x8*)&HS[SWZ(mt * 16 + l15, kc * 4 + q)];
#pragma unroll
        for (int s = 0; s < 3; ++s)
#pragma unroll
            for (int kc = 0; kc < 4; ++kc)
                accI[mt][s] = __builtin_amdgcn_mfma_f32_16x16x32_bf16(a[kc], bU[s][kc], accI[mt][s], 0, 0, 0);
    }
#pragma unroll
    for (int ct = 0; ct < 4; ++ct) {
        bf16x8 a[4];
#pragma unroll
        for (int kc = 0; kc < 4; ++kc)
            a[kc] = *(const bf16x8*)&Hc[SWZ(ct * 16 + l15, kc * 4 + q)];
#pragma unroll
        for (int kc = 0; kc < 4; ++kc)
            accF[ct] = __builtin_amdgcn_mfma_f32_16x16x32_bf16(a[kc], bU[3][kc], accF[ct], 0, 0, 0);
    }

    const int colf = w * 16 + l15;
#pragma unroll
    for (int ct = 0; ct < 4; ++ct) {
        float fc[4];
#pragma unroll
        for (int r = 0; r < 4; ++r) {
            int cl = ct * 16 + q * 4 + r;
            int pl = cl >> 1;
            float wxf = bf2f(wx[(size_t)(vp + pl) * 512 + 384 + colf]);
            float cch = c[(size_t)(vc + cl) * 128 + colf];
            fc[r] = sigmoidf_(accF[ct][r] + wxf) * cch;
        }
        PS[(ct * 8 + q * 2) * 128 + colf]     = fc[0] + fc[1];
        PS[(ct * 8 + q * 2 + 1) * 128 + colf] = fc[2] + fc[3];
    }
    __syncthreads();

#pragma unroll
    for (int mt = 0; mt < 2; ++mt) {
#pragma unroll
        for (int r = 0; r < 4; ++r) {
            int pl = mt * 16 + q * 4 + r;
            if (pl < P) {
                size_t vr = (size_t)(vp + pl);
                float wi = bf2f(wx[vr * 512 + colf]);
                float wo = bf2f(wx[vr * 512 + 128 + colf]);
                float wu = bf2f(wx[vr * 512 + 256 + colf]);
                float iv = sigmoidf_(accI[mt][0][r] + wi);
                float ov = sigmoidf_(accI[mt][1][r] + wo);
                float uv = tanhf_(accI[mt][2][r] + wu);
                float cn = iv * uv + PS[pl * 128 + colf];
                c[vr * 128 + colf] = cn;
                h[vr * 128 + colf] = ov * tanhf_(cn);
            }
        }
    }
}

__global__ __launch_bounds__(512, 2) void big_level_k(const uint16_t* __restrict__ wx,
                                                      const uint16_t* __restrict__ UT,
                                                      float* __restrict__ h,
                                                      float* __restrict__ c,
                                                      int dep) {
    __shared__ uint16_t Hc[64 * 128];
    __shared__ uint16_t HS[32 * 128];
    __shared__ float PS[32 * 128];
    bf16x8 bU[4][4];
    load_bU(UT, bU);
    int idx0 = blockIdx.x * 32;
    int tree = idx0 >> dep;
    int pos0 = idx0 - (tree << dep);
    int vp = tree * MTREE + ((1 << dep) - 1) + pos0;
    int vc = tree * MTREE + ((2 << dep) - 1) + 2 * pos0;
    climb_group(wx, h, c, Hc, HS, PS, bU, vp, vc, 32);
}

// ---------------------------------------------------------------------------
// Tail: dep 6..0, one block per tree. h double-buffered in LDS (bf16),
// c carried in lane registers, wx prefetched before the MFMAs.
// Global c read only for dep-7 children; global h written (output) only.
__global__ __launch_bounds__(512, 1) void tail_k(const uint16_t* __restrict__ wx,
                                                 const uint16_t* __restrict__ UT,
                                                 const float* __restrict__ cglob,
                                                 float* __restrict__ h) {
    __shared__ uint16_t bufA[128 * 128];  // 32 KB
    __shared__ uint16_t bufB[64 * 128];   // 16 KB
    __shared__ float PS[32 * 128];        // 16 KB
    bf16x8 bU[4][4];
    load_bU(UT, bU);
    const int tree = blockIdx.x;
    const int tid = threadIdx.x;
    const int w = tid >> 6, lane = tid & 63, q = lane >> 4, l15 = lane & 15;
    const int colf = w * 16 + l15;
    const int vbase = tree * MTREE;

    // stage dep-7 h (tree-local nodes 127..254) into bufA rows 0..127
#pragma unroll
    for (int t = 0; t < 4; ++t) {
        int ci = t * 512 + tid;             // 2048 chunks
        int row = ci >> 4, cx = ci & 15;
        const float* src = h + (size_t)(vbase + 127 + row) * 128 + cx * 8;
        float4 f0 = *(const float4*)src;
        float4 f1 = *(const float4*)(src + 4);
        *(uint4*)&bufA[SWZ(row, cx)] = pack_bf8(f0, f1);
    }

    float cStore[4][4];
#pragma unroll
    for (int a = 0; a < 4; ++a)
#pragma unroll
        for (int b = 0; b < 4; ++b) cStore[a][b] = 0.0f;

#pragma unroll
    for (int dep = 6; dep >= 0; --dep) {
        const int np = 1 << dep;
        const int groups = (np + 31) / 32;
        const int parity = (6 - dep) & 1;   // 0: children in bufA
#pragma unroll
        for (int g = 0; g < groups; ++g) {
            int pos0 = g * 32;
            int P = np - pos0; P = P < 32 ? P : 32;
            int vp = vbase + (np - 1) + pos0;
            uint16_t* hChild = parity ? bufB : bufA;
            uint16_t* hPar   = parity ? bufA : bufB;
            __syncthreads();                 // prev writes visible; PS reusable

            // ---- prefetch wx (latency overlaps the MFMAs below) ----
            float wxf_v[4][2], wi_v[2][4], wo_v[2][4], wu_v[2][4];
#pragma unroll
            for (int ct = 0; ct < 4; ++ct) {
#pragma unroll
                for (int pr = 0; pr < 2; ++pr) {   // two parents per (ct,q)
                    int pl = (ct * 16 + q * 4) / 2 + pr;
                    int pc = pl < P ? pl : 0;
                    wxf_v[ct][pr] = bf2f(wx[(size_t)(vp + pc) * 512 + 384 + colf]);
                }
            }
#pragma unroll
            for (int mt = 0; mt < 2; ++mt) {
#pragma unroll
                for (int r = 0; r < 4; ++r) {
                    int pl = mt * 16 + q * 4 + r;
                    int pc = pl < P ? pl : 0;
                    size_t vr = (size_t)(vp + pc);
                    wi_v[mt][r] = bf2f(wx[vr * 512 + colf]);
                    wo_v[mt][r] = bf2f(wx[vr * 512 + 128 + colf]);
                    wu_v[mt][r] = bf2f(wx[vr * 512 + 256 + colf]);
                }
            }

            // ---- matvecs (A from LDS child buffer, B resident) ----
            f32x4 accI[2][3] = {};
            f32x4 accF[4] = {};
#pragma unroll
            for (int mt = 0; mt < 2; ++mt) {
#pragma unroll
                for (int kc = 0; kc < 4; ++kc) {
                    int p = pos0 + mt * 16 + l15;       // level-local parent
                    bf16x8 a0 = *(const bf16x8*)&hChild[SWZ(2 * p, kc * 4 + q)];
                    bf16x8 a1 = *(const bf16x8*)&hChild[SWZ(2 * p + 1, kc * 4 + q)];
                    bf16x8 a = bfadd8(a0, a1);
#pragma unroll
                    for (int s = 0; s < 3; ++s)
                        accI[mt][s] = __builtin_amdgcn_mfma_f32_16x16x32_bf16(a, bU[s][kc], accI[mt][s], 0, 0, 0);
                }
            }
#pragma unroll
            for (int ct = 0; ct < 4; ++ct) {
#pragma unroll
                for (int kc = 0; kc < 4; ++kc) {
                    int crow = 2 * pos0 + ct * 16 + l15;  // level-local child
                    bf16x8 a = *(const bf16x8*)&hChild[SWZ(crow, kc * 4 + q)];
                    accF[ct] = __builtin_amdgcn_mfma_f32_16x16x32_bf16(a, bU[3][kc], accF[ct], 0, 0, 0);
                }
            }

            // ---- f epilogue: pair-sum f*c into PS ----
#pragma unroll
            for (int ct = 0; ct < 4; ++ct) {
                float fc[4];
#pragma unroll
                for (int r = 0; r < 4; ++r) {
                    int cl = ct * 16 + q * 4 + r;          // group-local child
                    float cch;
                    if (dep == 6) {
                        int clev = 2 * pos0 + cl;
                        cch = cglob[(size_t)(vbase + 127 + clev) * 128 + colf];
                    } else {
                        cch = cStore[(2 * pos0 + cl) >> 4][r];
                    }
                    fc[r] = sigmoidf_(accF[ct][r] + wxf_v[ct][r >> 1]) * cch;
                }
                PS[(ct * 8 + q * 2) * 128 + colf]     = fc[0] + fc[1];
                PS[(ct * 8 + q * 2 + 1) * 128 + colf] = fc[2] + fc[3];
            }
            __syncthreads();

            // ---- combine ----
            float cNew[2][4];
#pragma unroll
            for (int mt = 0; mt < 2; ++mt) {
#pragma unroll
                for (int r = 0; r < 4; ++r) {
                    int pl = mt * 16 + q * 4 + r;
                    float iv = sigmoidf_(accI[mt][0][r] + wi_v[mt][r]);
                    float ov = sigmoidf_(accI[mt][1][r] + wo_v[mt][r]);
                    float uv = tanhf_(accI[mt][2][r] + wu_v[mt][r]);
                    float cn = iv * uv + PS[pl * 128 + colf];
                    float hv = ov * tanhf_(cn);
                    cNew[mt][r] = cn;
                    if (pl < P) {
                        int p = pos0 + pl;                  // level-local parent
                        h[(size_t)(vbase + (np - 1) + p) * 128 + colf] = hv;
                        int chunk = colf >> 3;
                        hPar[p * 128 + ((chunk ^ (p & 7)) * 8) + (colf & 7)] = f2bf(hv);
                    }
                }
            }
#pragma unroll
            for (int mt = 0; mt < 2; ++mt)
#pragma unroll
                for (int r = 0; r < 4; ++r)
                    if (mt * 16 + q * 4 + r < P) cStore[g * 2 + mt][r] = cNew[mt][r];
        }
    }
}

// ---------------------------------------------------------------------------
extern "C" void kernel_launch(void* const* d_in, const int* in_sizes, int n_in,
                              void* d_out, int out_size, void* d_ws, size_t ws_size,
                              hipStream_t stream) {
    const float* features = (const float*)d_in[0];
    const float* W_iou    = (const float*)d_in[1];
    const float* b_iou    = (const float*)d_in[2];
    const float* U_iou    = (const float*)d_in[3];
    const float* W_f      = (const float*)d_in[4];
    const float* b_f      = (const float*)d_in[5];
    const float* U_f      = (const float*)d_in[6];
    float* h = (float*)d_out;

    char* wp = (char*)d_ws;
    uint16_t* wx    = (uint16_t*)wp; wp += (size_t)NNODES * 512 * 2;
    float*    c     = (float*)wp;    wp += (size_t)NNODES * 128 * 4;
    uint16_t* WT    = (uint16_t*)wp; wp += 512 * 128 * 2;
    uint16_t* UT    = (uint16_t*)wp; wp += 512 * 128 * 2;
    float*    biasS = (float*)wp;    wp += 512 * 4;

    hipLaunchKernelGGL(prep_k, dim3(1025), dim3(128), 0, stream,
                       W_iou, W_f, U_iou, U_f, b_iou, b_f, WT, UT, biasS);
    hipLaunchKernelGGL(gemm_leaf_k, dim3(1024), dim3(512), 0, stream,
                       features, WT, biasS, wx, h, c);
    hipLaunchKernelGGL(big_level_k, dim3(512), dim3(512), 0, stream, wx, UT, h, c, 9);
    hipLaunchKernelGGL(big_level_k, dim3(256), dim3(512), 0, stream, wx, UT, h, c, 8);
    hipLaunchKernelGGL(big_level_k, dim3(128), dim3(512), 0, stream, wx, UT, h, c, 7);
    hipLaunchKernelGGL(tail_k, dim3(32), dim3(512), 0, stream, wx, UT, c, h);
}

// Round 6
// 208.096 us; speedup vs baseline: 1.1440x; 1.1440x over previous
//
#include <hip/hip_runtime.h>
#include <math.h>
#include <stdint.h>

// TreeLSTM, 32 complete binary trees depth 10, heap order, d=128.
// R6: per-CHILD iou matvec (reuses f's A-frags; parent = in-register f32
//     pair-sum of adjacent acc regs) -> kills bfadd8 repack VALU, kills the
//     PS LDS round-trip and the second barrier. Tail carries c in LDS (CS,
//     double-buffered halves). R5's tail was VALU-throughput-bound on 32 CUs.

#define NTREES 32
#define MTREE 2047
#define NNODES (NTREES * MTREE)   // 65504

typedef __attribute__((ext_vector_type(8))) short bf16x8;
typedef __attribute__((ext_vector_type(4))) float f32x4;

__device__ __forceinline__ float sigmoidf_(float x) {
    return 1.0f / (1.0f + __expf(-x));
}
__device__ __forceinline__ float tanhf_(float x) {
    x = fminf(fmaxf(x, -10.0f), 10.0f);
    float e = __expf(2.0f * x);
    return (e - 1.0f) / (e + 1.0f);
}
__device__ __forceinline__ float bf2f(uint16_t b) {
    union { uint32_t u; float f; } v; v.u = ((uint32_t)b) << 16; return v.f;
}
__device__ __forceinline__ uint16_t f2bf(float f) {
    union { float f; uint32_t u; } v; v.f = f;
    uint32_t r = v.u + 0x7FFF + ((v.u >> 16) & 1);   // RNE
    return (uint16_t)(r >> 16);
}
__device__ __forceinline__ uint4 pack_bf8(float4 a, float4 b) {
    uint4 r;
    r.x = (uint32_t)f2bf(a.x) | ((uint32_t)f2bf(a.y) << 16);
    r.y = (uint32_t)f2bf(a.z) | ((uint32_t)f2bf(a.w) << 16);
    r.z = (uint32_t)f2bf(b.x) | ((uint32_t)f2bf(b.y) << 16);
    r.w = (uint32_t)f2bf(b.z) | ((uint32_t)f2bf(b.w) << 16);
    return r;
}

// Swizzled LDS layout: bf16 rows of 128 (16 chunks of 16B), XOR by row&7.
#define SWZ(row, chunk) ((row) * 128 + (((chunk) ^ ((row) & 7)) * 8))

// ---------------------------------------------------------------------------
__global__ __launch_bounds__(128) void prep_k(const float* __restrict__ Wiou,
                                              const float* __restrict__ Wf,
                                              const float* __restrict__ Uiou,
                                              const float* __restrict__ Uf,
                                              const float* __restrict__ biou,
                                              const float* __restrict__ bf,
                                              uint16_t* __restrict__ WT,
                                              uint16_t* __restrict__ UT,
                                              float* __restrict__ biasS) {
    int n = blockIdx.x, k = threadIdx.x;
    if (n < 512) {
        WT[n * 128 + k] = f2bf(n < 384 ? Wiou[k * 384 + n] : Wf[k * 128 + (n - 384)]);
    } else if (n < 1024) {
        int m = n - 512;
        UT[m * 128 + k] = f2bf(m < 384 ? Uiou[k * 384 + m] : Uf[k * 128 + (m - 384)]);
    } else {
#pragma unroll
        for (int r = 0; r < 4; ++r) {
            int j = r * 128 + k;
            biasS[j] = j < 384 ? biou[j] : bf[j - 384];
        }
    }
}

// ---------------------------------------------------------------------------
// Fused GEMM + leaf epilogue (unchanged from R3/R5 — correct & adequate).
__global__ __launch_bounds__(512, 2) void gemm_leaf_k(const float* __restrict__ F,
                                                      const uint16_t* __restrict__ WT,
                                                      const float* __restrict__ biasS,
                                                      uint16_t* __restrict__ wx,
                                                      float* __restrict__ h,
                                                      float* __restrict__ c) {
    __shared__ uint16_t Fs[64 * 128];
    const int tid = threadIdx.x;
    const int w = tid >> 6, lane = tid & 63, q = lane >> 4, l15 = lane & 15;
    const int n0 = blockIdx.x * 64;

#pragma unroll
    for (int r = 0; r < 2; ++r) {
        int ci = r * 512 + tid;
        int row = ci >> 4, cx = ci & 15;
        int v = n0 + row; v = v < NNODES ? v : NNODES - 1;
        const float* src = F + (size_t)v * 128 + cx * 8;
        float4 f0 = *(const float4*)src;
        float4 f1 = *(const float4*)(src + 4);
        *(uint4*)&Fs[SWZ(row, cx)] = pack_bf8(f0, f1);
    }
    bf16x8 aW[4][4];
    float4 bias4[4];
#pragma unroll
    for (int s = 0; s < 4; ++s) {
        int row = (w + s * 8) * 16 + l15;
#pragma unroll
        for (int kc = 0; kc < 4; ++kc)
            aW[s][kc] = *(const bf16x8*)(WT + (size_t)row * 128 + kc * 32 + q * 8);
        bias4[s] = *(const float4*)(biasS + (w + s * 8) * 16 + q * 4);
    }
    __syncthreads();

#pragma unroll
    for (int nt = 0; nt < 4; ++nt) {
        bf16x8 b[4];
#pragma unroll
        for (int kc = 0; kc < 4; ++kc)
            b[kc] = *(const bf16x8*)&Fs[SWZ(nt * 16 + l15, kc * 4 + q)];
        f32x4 acc[4] = {};
#pragma unroll
        for (int s = 0; s < 4; ++s)
#pragma unroll
            for (int kc = 0; kc < 4; ++kc)
                acc[s] = __builtin_amdgcn_mfma_f32_16x16x32_bf16(aW[s][kc], b[kc], acc[s], 0, 0, 0);

        int node = n0 + nt * 16 + l15;
        bool nvalid = node < NNODES;
        int v = nvalid ? node : NNODES - 1;
        int tree = v / 2047;
        int j = v - tree * 2047;
        bool leaf = j >= 1023;
        float pi[4], po[4], pu[4], pf[4];
#pragma unroll
        for (int r = 0; r < 4; ++r) {
            pi[r] = acc[0][r] + bias4[0][r];
            po[r] = acc[1][r] + bias4[1][r];
            pu[r] = acc[2][r] + bias4[2][r];
            pf[r] = acc[3][r] + bias4[3][r];
        }
        int colb = w * 16 + q * 4;
        if (nvalid && leaf) {
            float cv[4], hv[4];
#pragma unroll
            for (int r = 0; r < 4; ++r) {
                float iv = sigmoidf_(pi[r]);
                float ov = sigmoidf_(po[r]);
                float uv = tanhf_(pu[r]);
                float cn = iv * uv;
                cv[r] = cn;
                hv[r] = ov * tanhf_(cn);
            }
            *(float4*)&c[(size_t)v * 128 + colb] = *(float4*)cv;
            *(float4*)&h[(size_t)v * 128 + colb] = *(float4*)hv;
        }
        if (nvalid && !leaf) {
            ushort4 s0 = make_ushort4(f2bf(pi[0]), f2bf(pi[1]), f2bf(pi[2]), f2bf(pi[3]));
            ushort4 s1 = make_ushort4(f2bf(po[0]), f2bf(po[1]), f2bf(po[2]), f2bf(po[3]));
            ushort4 s2 = make_ushort4(f2bf(pu[0]), f2bf(pu[1]), f2bf(pu[2]), f2bf(pu[3]));
            ushort4 s3 = make_ushort4(f2bf(pf[0]), f2bf(pf[1]), f2bf(pf[2]), f2bf(pf[3]));
            uint16_t* wr = wx + (size_t)v * 512 + colb;
            *(ushort4*)(wr)       = s0;
            *(ushort4*)(wr + 128) = s1;
            *(ushort4*)(wr + 256) = s2;
            *(ushort4*)(wr + 384) = s3;
        }
    }
}

// ---------------------------------------------------------------------------
__device__ __forceinline__ void load_bU(const uint16_t* __restrict__ UT, bf16x8 bU[4][4]) {
    const int tid = threadIdx.x;
    const int w = tid >> 6, lane = tid & 63, q = lane >> 4, l15 = lane & 15;
#pragma unroll
    for (int s = 0; s < 4; ++s) {
        int row = (w + s * 8) * 16 + l15;   // s: 0=i,1=o,2=u,3=f column blocks
#pragma unroll
        for (int kc = 0; kc < 4; ++kc)
            bU[s][kc] = *(const bf16x8*)(UT + (size_t)row * 128 + kc * 32 + q * 8);
    }
}

// ---------------------------------------------------------------------------
// Big levels (dep 9/8/7): 32 parents (64 children) per block, grid-parallel.
// Per-child matvec for all 4 gates; parent = in-lane f32 pair-sum. One barrier.
__global__ __launch_bounds__(512, 2) void big_level_k(const uint16_t* __restrict__ wx,
                                                      const uint16_t* __restrict__ UT,
                                                      float* __restrict__ h,
                                                      float* __restrict__ c,
                                                      int dep) {
    __shared__ uint16_t Hc[64 * 128];   // 16 KB
    bf16x8 bU[4][4];
    load_bU(UT, bU);
    const int tid = threadIdx.x;
    const int w = tid >> 6, lane = tid & 63, q = lane >> 4, l15 = lane & 15;
    const int colf = w * 16 + l15;
    int idx0 = blockIdx.x * 32;
    int tree = idx0 >> dep;
    int pos0 = idx0 - (tree << dep);
    int np = 1 << dep;
    int vp = tree * MTREE + (np - 1) + pos0;
    int vc = tree * MTREE + (2 * np - 1) + 2 * pos0;

    // scattered wx + child-c loads issued first (latency hides under staging+MFMA)
    float wxg[4][2][4];
#pragma unroll
    for (int ct = 0; ct < 4; ++ct)
#pragma unroll
        for (int j = 0; j < 2; ++j) {
            int pl = ct * 8 + q * 2 + j;
            const uint16_t* base = wx + (size_t)(vp + pl) * 512 + colf;
            wxg[ct][j][0] = bf2f(base[0]);
            wxg[ct][j][1] = bf2f(base[128]);
            wxg[ct][j][2] = bf2f(base[256]);
            wxg[ct][j][3] = bf2f(base[384]);
        }
    float cch[4][4];
#pragma unroll
    for (int ct = 0; ct < 4; ++ct)
#pragma unroll
        for (int r = 0; r < 4; ++r) {
            int cl = ct * 16 + q * 4 + r;
            cch[ct][r] = c[(size_t)(vc + cl) * 128 + colf];
        }

    // stage 64 child-h rows f32 -> bf16 swizzled
#pragma unroll
    for (int t = 0; t < 2; ++t) {
        int ci = t * 512 + tid;          // 1024 chunks
        int row = ci >> 4, cx = ci & 15;
        const float* src = h + (size_t)(vc + row) * 128 + cx * 8;
        float4 f0 = *(const float4*)src;
        float4 f1 = *(const float4*)(src + 4);
        *(uint4*)&Hc[SWZ(row, cx)] = pack_bf8(f0, f1);
    }
    __syncthreads();

    // per-child matvec: 4 child-tiles x 4 gates x 4 k-chunks
    f32x4 acc[4][4] = {};
#pragma unroll
    for (int ct = 0; ct < 4; ++ct) {
        bf16x8 a[4];
#pragma unroll
        for (int kc = 0; kc < 4; ++kc)
            a[kc] = *(const bf16x8*)&Hc[SWZ(ct * 16 + l15, kc * 4 + q)];
#pragma unroll
        for (int s = 0; s < 4; ++s)
#pragma unroll
            for (int kc = 0; kc < 4; ++kc)
                acc[ct][s] = __builtin_amdgcn_mfma_f32_16x16x32_bf16(a[kc], bU[s][kc], acc[ct][s], 0, 0, 0);
    }

    // lane-local epilogue: f per child, pair-sum everything per parent
#pragma unroll
    for (int ct = 0; ct < 4; ++ct) {
        float fc[4];
#pragma unroll
        for (int r = 0; r < 4; ++r)
            fc[r] = sigmoidf_(acc[ct][3][r] + wxg[ct][r >> 1][3]) * cch[ct][r];
#pragma unroll
        for (int j = 0; j < 2; ++j) {
            int pl = ct * 8 + q * 2 + j;
            float ip = acc[ct][0][2 * j] + acc[ct][0][2 * j + 1] + wxg[ct][j][0];
            float op = acc[ct][1][2 * j] + acc[ct][1][2 * j + 1] + wxg[ct][j][1];
            float up = acc[ct][2][2 * j] + acc[ct][2][2 * j + 1] + wxg[ct][j][2];
            float cn = sigmoidf_(ip) * tanhf_(up) + fc[2 * j] + fc[2 * j + 1];
            float hv = sigmoidf_(op) * tanhf_(cn);
            c[(size_t)(vp + pl) * 128 + colf] = cn;
            h[(size_t)(vp + pl) * 128 + colf] = hv;
        }
    }
}

// ---------------------------------------------------------------------------
// Tail: dep 6..0, one block per tree, 8 groups, one barrier per group.
// h in LDS (Hbuf rows 0..127 / 128..191 alternating), c in LDS CS halves.
__global__ __launch_bounds__(512, 1) void tail_k(const uint16_t* __restrict__ wx,
                                                 const uint16_t* __restrict__ UT,
                                                 const float* __restrict__ cglob,
                                                 float* __restrict__ h) {
    __shared__ uint16_t Hbuf[192 * 128];   // 48 KB
    __shared__ float CS[128 * 132];        // 66 KB, stride 132 (2-way-free banks)
    bf16x8 bU[4][4];
    load_bU(UT, bU);
    const int tree = blockIdx.x;
    const int tid = threadIdx.x;
    const int w = tid >> 6, lane = tid & 63, q = lane >> 4, l15 = lane & 15;
    const int colf = w * 16 + l15;
    const int vbase = tree * MTREE;

    // stage dep-7 h (tree-local nodes 127..254) into Hbuf rows 0..127
#pragma unroll
    for (int t = 0; t < 4; ++t) {
        int ci = t * 512 + tid;
        int row = ci >> 4, cx = ci & 15;
        const float* src = h + (size_t)(vbase + 127 + row) * 128 + cx * 8;
        float4 f0 = *(const float4*)src;
        float4 f1 = *(const float4*)(src + 4);
        *(uint4*)&Hbuf[SWZ(row, cx)] = pack_bf8(f0, f1);
    }

#pragma unroll 1
    for (int gi = 0; gi < 8; ++gi) {
        const int dep = gi < 2 ? 6 : 7 - gi;
        const int np = 1 << dep;
        const int pos0 = (gi == 1) ? 32 : 0;
        const int P = gi < 3 ? 32 : np;
        const int pL = dep & 1;              // 0 for dep 6,4,2,0
        const int childBase = pL ? 128 : 0;
        const int parBase = pL ? 0 : 128;
        const int csRead = pL ? 0 : 64;
        const int csWrite = pL ? 64 : 0;
        const int vp = vbase + (np - 1) + pos0;
        __syncthreads();

        // wx for this lane's 8 parents (4 gates each)
        float wxg[4][2][4];
#pragma unroll
        for (int ct = 0; ct < 4; ++ct)
#pragma unroll
            for (int j = 0; j < 2; ++j) {
                int pl = ct * 8 + q * 2 + j;
                const uint16_t* base = wx + (size_t)(vp + pl) * 512 + colf;
                wxg[ct][j][0] = bf2f(base[0]);
                wxg[ct][j][1] = bf2f(base[128]);
                wxg[ct][j][2] = bf2f(base[256]);
                wxg[ct][j][3] = bf2f(base[384]);
            }
        // child c: global (dep6) or CS (below)
        float cch[4][4];
        if (gi < 2) {
#pragma unroll
            for (int ct = 0; ct < 4; ++ct)
#pragma unroll
                for (int r = 0; r < 4; ++r) {
                    int cl = 2 * pos0 + ct * 16 + q * 4 + r;
                    cch[ct][r] = cglob[(size_t)(vbase + 127 + cl) * 128 + colf];
                }
        } else {
#pragma unroll
            for (int ct = 0; ct < 4; ++ct)
#pragma unroll
                for (int r = 0; r < 4; ++r) {
                    int cl = ct * 16 + q * 4 + r;
                    cch[ct][r] = CS[(csRead + cl) * 132 + colf];
                }
        }

        // per-child matvec
        f32x4 acc[4][4] = {};
#pragma unroll
        for (int ct = 0; ct < 4; ++ct) {
            bf16x8 a[4];
#pragma unroll
            for (int kc = 0; kc < 4; ++kc) {
                int row = childBase + 2 * pos0 + ct * 16 + l15;
                a[kc] = *(const bf16x8*)&Hbuf[SWZ(row, kc * 4 + q)];
            }
#pragma unroll
            for (int s = 0; s < 4; ++s)
#pragma unroll
                for (int kc = 0; kc < 4; ++kc)
                    acc[ct][s] = __builtin_amdgcn_mfma_f32_16x16x32_bf16(a[kc], bU[s][kc], acc[ct][s], 0, 0, 0);
        }

        // lane-local epilogue
#pragma unroll
        for (int ct = 0; ct < 4; ++ct) {
            float fc[4];
#pragma unroll
            for (int r = 0; r < 4; ++r)
                fc[r] = sigmoidf_(acc[ct][3][r] + wxg[ct][r >> 1][3]) * cch[ct][r];
#pragma unroll
            for (int j = 0; j < 2; ++j) {
                int pl = ct * 8 + q * 2 + j;
                float ip = acc[ct][0][2 * j] + acc[ct][0][2 * j + 1] + wxg[ct][j][0];
                float op = acc[ct][1][2 * j] + acc[ct][1][2 * j + 1] + wxg[ct][j][1];
                float up = acc[ct][2][2 * j] + acc[ct][2][2 * j + 1] + wxg[ct][j][2];
                float cn = sigmoidf_(ip) * tanhf_(up) + fc[2 * j] + fc[2 * j + 1];
                float hv = sigmoidf_(op) * tanhf_(cn);
                if (pl < P) {
                    h[(size_t)(vp + pl) * 128 + colf] = hv;
                    int row = parBase + pos0 + pl;       // next level's child row
                    Hbuf[row * 128 + (((colf >> 3) ^ (row & 7)) * 8) + (colf & 7)] = f2bf(hv);
                    CS[(csWrite + pos0 + pl) * 132 + colf] = cn;
                }
            }
        }
    }
}

// ---------------------------------------------------------------------------
extern "C" void kernel_launch(void* const* d_in, const int* in_sizes, int n_in,
                              void* d_out, int out_size, void* d_ws, size_t ws_size,
                              hipStream_t stream) {
    const float* features = (const float*)d_in[0];
    const float* W_iou    = (const float*)d_in[1];
    const float* b_iou    = (const float*)d_in[2];
    const float* U_iou    = (const float*)d_in[3];
    const float* W_f      = (const float*)d_in[4];
    const float* b_f      = (const float*)d_in[5];
    const float* U_f      = (const float*)d_in[6];
    float* h = (float*)d_out;

    char* wp = (char*)d_ws;
    uint16_t* wx    = (uint16_t*)wp; wp += (size_t)NNODES * 512 * 2;
    float*    c     = (float*)wp;    wp += (size_t)NNODES * 128 * 4;
    uint16_t* WT    = (uint16_t*)wp; wp += 512 * 128 * 2;
    uint16_t* UT    = (uint16_t*)wp; wp += 512 * 128 * 2;
    float*    biasS = (float*)wp;    wp += 512 * 4;

    hipLaunchKernelGGL(prep_k, dim3(1025), dim3(128), 0, stream,
                       W_iou, W_f, U_iou, U_f, b_iou, b_f, WT, UT, biasS);
    hipLaunchKernelGGL(gemm_leaf_k, dim3(1024), dim3(512), 0, stream,
                       features, WT, biasS, wx, h, c);
    hipLaunchKernelGGL(big_level_k, dim3(512), dim3(512), 0, stream, wx, UT, h, c, 9);
    hipLaunchKernelGGL(big_level_k, dim3(256), dim3(512), 0, stream, wx, UT, h, c, 8);
    hipLaunchKernelGGL(big_level_k, dim3(128), dim3(512), 0, stream, wx, UT, h, c, 7);
    hipLaunchKernelGGL(tail_k, dim3(32), dim3(512), 0, stream, wx, UT, c, h);
}